// Round 2
// baseline (39.148 us; speedup 1.0000x reference)
//
#include <hip/hip_runtime.h>
#include <hip/hip_bf16.h>

// ---------------------------------------------------------------------------
// VQC_Net: probs[b, c] = ( U @ amp[b] )^2 [c],  c = 0..9
// Factorized: U = RY2 * D * RY1 applied as per-qubit butterflies.
//   RY layer, qubit q, pair (i, i|1<<q):  [c,-s; s,c]
//   D = diag sign: -1 exactly at k in {3, 6, 9, 12}
// Only loop-invariant data: 16 cos/sin scalars (built by tiny kernel in d_ws).
// amp build:
//   amp[0][k]  = prod_j ( (k>>j)&1 ? x0j : 1-x0j )                 (no sqrt)
//   amp[b][k]  = sqrt( prod_j ( (k>>(3-j))&1 ? xj^2 : 1-xj^2 ) )   (b >= 1)
// ---------------------------------------------------------------------------

// cs[0..3]=cos(th[q]/2) layer1, cs[4..7]=cos layer2, cs[8..11]=sin layer1,
// cs[12..15]=sin layer2
__global__ void build_cs(const float* __restrict__ theta, float* __restrict__ cs) {
    int t = threadIdx.x;
    if (t < 8) {
        float h = 0.5f * theta[t];
        cs[t]     = cosf(h);
        cs[8 + t] = sinf(h);
    }
}

__global__ __launch_bounds__(256) void vqc_main(const float4* __restrict__ x,
                                                const float* __restrict__ CS,
                                                float* __restrict__ out,
                                                int nsamp) {
    __shared__ float sOut[2560];  // 256 samples x 10 outputs, coalesced flush

    int tid = threadIdx.x;
    long long b = (long long)blockIdx.x * 256 + tid;

    // 16 uniform scalars, loaded once (compiler scalarizes: uniform ptr+idx)
    float c10 = CS[0],  c11 = CS[1],  c12 = CS[2],  c13 = CS[3];
    float c20 = CS[4],  c21 = CS[5],  c22 = CS[6],  c23 = CS[7];
    float s10 = CS[8],  s11 = CS[9],  s12 = CS[10], s13 = CS[11];
    float s20 = CS[12], s21 = CS[13], s22 = CS[14], s23 = CS[15];

    if (b < nsamp) {
        float4 xv = x[b];
        float amp[16];

        if (b == 0) {
            // little-endian bits, raw products, no sqrt
            float f0a = 1.0f - xv.x, f0b = xv.x;
            float f1a = 1.0f - xv.y, f1b = xv.y;
            float f2a = 1.0f - xv.z, f2b = xv.z;
            float f3a = 1.0f - xv.w, f3b = xv.w;
            float lo[4] = { f0a * f1a, f0b * f1a, f0a * f1b, f0b * f1b };
            float hi[4] = { f2a * f3a, f2b * f3a, f2a * f3b, f2b * f3b };
#pragma unroll
            for (int k = 0; k < 16; ++k)
                amp[k] = lo[k & 3] * hi[k >> 2];
        } else {
            // big-endian bits, squared probs, sqrt
            float p0 = xv.x * xv.x, p1 = xv.y * xv.y;
            float p2 = xv.z * xv.z, p3 = xv.w * xv.w;
            float f0a = 1.0f - p0, f0b = p0;
            float f1a = 1.0f - p1, f1b = p1;
            float f2a = 1.0f - p2, f2b = p2;
            float f3a = 1.0f - p3, f3b = p3;
            float hi[4] = { f0a * f1a, f0a * f1b, f0b * f1a, f0b * f1b };
            float lo[4] = { f2a * f3a, f2a * f3b, f2b * f3a, f2b * f3b };
#pragma unroll
            for (int k = 0; k < 16; ++k)
                amp[k] = sqrtf(hi[k >> 2] * lo[k & 3]);
        }

        // ---- RY1 butterflies (qubit q uses bit q of the index) ----
#define BFLY(Q, CC, SS)                                                  \
        _Pragma("unroll")                                                \
        for (int i0 = 0; i0 < 16; ++i0)                                  \
            if (!(i0 & (1 << (Q)))) {                                    \
                int i1 = i0 | (1 << (Q));                                \
                float a0 = amp[i0], a1 = amp[i1];                        \
                amp[i0] = fmaf((CC), a0, -(SS) * a1);                    \
                amp[i1] = fmaf((SS), a0,  (CC) * a1);                    \
            }

        BFLY(0, c10, s10)
        BFLY(1, c11, s11)
        BFLY(2, c12, s12)
        BFLY(3, c13, s13)

        // ---- D: sign flips at k = 3, 6, 9, 12 ----
        amp[3]  = -amp[3];
        amp[6]  = -amp[6];
        amp[9]  = -amp[9];
        amp[12] = -amp[12];

        // ---- RY2 butterflies, qubit 3 last (only 10 outputs needed) ----
        BFLY(0, c20, s20)
        BFLY(1, c21, s21)
        BFLY(2, c22, s22)
#undef BFLY

        float r[10];
#pragma unroll
        for (int i = 0; i < 8; ++i)
            r[i] = fmaf(c23, amp[i], -s23 * amp[i + 8]);   // row0 of q3 pair
        r[8] = fmaf(s23, amp[0], c23 * amp[8]);            // row1, pair (0,8)
        r[9] = fmaf(s23, amp[1], c23 * amp[9]);            // row1, pair (1,9)

#pragma unroll
        for (int c = 0; c < 10; ++c)
            sOut[tid * 10 + c] = r[c] * r[c];
    }
    __syncthreads();

    long long blockStart = (long long)blockIdx.x * 256;
    long long remain = (long long)nsamp - blockStart;
    if (remain >= 256) {
        // full block: 2560 contiguous floats, 16B-aligned base
        float4* ov = (float4*)(out + blockStart * 10);
        const float4* sv = (const float4*)sOut;
#pragma unroll
        for (int i = tid; i < 640; i += 256)
            ov[i] = sv[i];
    } else if (remain > 0) {
        int n = (int)remain * 10;
        for (int i = tid; i < n; i += 256)
            out[blockStart * 10 + i] = sOut[i];
    }
}

extern "C" void kernel_launch(void* const* d_in, const int* in_sizes, int n_in,
                              void* d_out, int out_size, void* d_ws, size_t ws_size,
                              hipStream_t stream) {
    const float* x = (const float*)d_in[0];      // [B,4] f32
    const float* theta = (const float*)d_in[1];  // [8]   f32
    float* out = (float*)d_out;                  // [B,10] f32
    float* cs = (float*)d_ws;                    // 16 floats scratch

    int nsamp = in_sizes[0] / 4;

    build_cs<<<1, 64, 0, stream>>>(theta, cs);

    int blocks = (nsamp + 255) / 256;
    vqc_main<<<blocks, 256, 0, stream>>>((const float4*)x, cs, out, nsamp);
}

// Round 3
// 38.598 us; speedup vs baseline: 1.0142x; 1.0142x over previous
//
#include <hip/hip_runtime.h>
#include <hip/hip_bf16.h>

// ---------------------------------------------------------------------------
// VQC_Net: probs[b, c] = ( sum_j U[c][j] * amp[b][j] )^2,  c = 0..9
// U = RY2 * D * RY1 (16x16, theta-only), precomputed TRANSPOSED into d_ws:
//   T[j*10 + c] = U[c][j]
// Main kernel: j-outer / c-inner matvec -> 10 independent acc chains,
// T values are wave-uniform scalar operands (s_load), shared by 2 samples.
// amp build:
//   amp[0][k]  = prod_j ( (k>>j)&1 ? x0j : 1-x0j )                 (no sqrt)
//   amp[b][k]  = prod sqrt-factored: sqrt(hi)*sqrt(lo), big-endian (b >= 1)
// ---------------------------------------------------------------------------

__device__ __forceinline__ float ry_el(float c, float s, int i, int j) {
    return (i == j) ? c : (i ? s : -s);  // ry = [[c,-s],[s,c]]
}

__global__ void build_T(const float* __restrict__ theta, float* __restrict__ T) {
    int t = threadIdx.x;
    if (t >= 160) return;
    int c = t >> 4;   // row of U (class)
    int j = t & 15;   // col of U (amp index)

    float co1[4], si1[4], co2[4], si2[4];
#pragma unroll
    for (int q = 0; q < 4; ++q) {
        float h1 = 0.5f * theta[q];
        float h2 = 0.5f * theta[4 + q];
        co1[q] = cosf(h1); si1[q] = sinf(h1);
        co2[q] = cosf(h2); si2[q] = sinf(h2);
    }

    float acc = 0.0f;
#pragma unroll
    for (int k = 0; k < 16; ++k) {
        int k0 = k & 1, k1 = (k >> 1) & 1, k2 = (k >> 2) & 1, k3 = (k >> 3) & 1;
        float r2 = ry_el(co2[0], si2[0], c & 1, k0)
                 * ry_el(co2[1], si2[1], (c >> 1) & 1, k1)
                 * ry_el(co2[2], si2[2], (c >> 2) & 1, k2)
                 * ry_el(co2[3], si2[3], (c >> 3) & 1, k3);
        float r1 = ry_el(co1[0], si1[0], k0, j & 1)
                 * ry_el(co1[1], si1[1], k1, (j >> 1) & 1)
                 * ry_el(co1[2], si1[2], k2, (j >> 2) & 1)
                 * ry_el(co1[3], si1[3], k3, (j >> 3) & 1);
        int sgn = (k0 & k1) ^ (k1 & k2) ^ (k2 & k3) ^ (k0 & k3);
        acc = fmaf(sgn ? -r2 : r2, r1, acc);
    }
    T[j * 10 + c] = acc;   // transposed
}

// amp for the generic (b>=1) path: big-endian bits, squared probs, sqrt
__device__ __forceinline__ void amp_resolve(float4 xv, float amp[16]) {
    float p0 = xv.x * xv.x, p1 = xv.y * xv.y;
    float p2 = xv.z * xv.z, p3 = xv.w * xv.w;
    // hi index h = k>>2: bit1 -> qubit0 (k bit3), bit0 -> qubit1 (k bit2)
    float hi[4] = { (1.0f - p0) * (1.0f - p1), (1.0f - p0) * p1,
                    p0 * (1.0f - p1),          p0 * p1 };
    // lo index l = k&3: bit1 -> qubit2 (k bit1), bit0 -> qubit3 (k bit0)
    float lo[4] = { (1.0f - p2) * (1.0f - p3), (1.0f - p2) * p3,
                    p2 * (1.0f - p3),          p2 * p3 };
    float sh[4], sl[4];
#pragma unroll
    for (int i = 0; i < 4; ++i) { sh[i] = sqrtf(hi[i]); sl[i] = sqrtf(lo[i]); }
#pragma unroll
    for (int k = 0; k < 16; ++k)
        amp[k] = sh[k >> 2] * sl[k & 3];
}

// amp for sample 0: little-endian bits, raw products, no sqrt
__device__ __forceinline__ void amp_prob2amp(float4 xv, float amp[16]) {
    float lo[4] = { (1.0f - xv.x) * (1.0f - xv.y), xv.x * (1.0f - xv.y),
                    (1.0f - xv.x) * xv.y,          xv.x * xv.y };
    float hi[4] = { (1.0f - xv.z) * (1.0f - xv.w), xv.z * (1.0f - xv.w),
                    (1.0f - xv.z) * xv.w,          xv.z * xv.w };
#pragma unroll
    for (int k = 0; k < 16; ++k)
        amp[k] = lo[k & 3] * hi[k >> 2];
}

#define SPB 512  // samples per block (2 per thread)

__global__ __launch_bounds__(256) void vqc_main(const float4* __restrict__ x,
                                                const float* __restrict__ T,
                                                float* __restrict__ out,
                                                int nsamp) {
    __shared__ float sOut[SPB * 10];  // 20 KB

    int tid = threadIdx.x;
    long long blockStart = (long long)blockIdx.x * SPB;
    long long b0 = blockStart + tid;
    long long b1 = blockStart + 256 + tid;

    bool v0 = b0 < nsamp, v1 = b1 < nsamp;

    // issue both loads up front (2 outstanding vmem / thread)
    float4 xv0, xv1;
    if (v0) xv0 = x[b0];
    if (v1) xv1 = x[b1];

    float amp0[16], amp1[16];
    if (v0) {
        if (b0 == 0) amp_prob2amp(xv0, amp0);
        else         amp_resolve(xv0, amp0);
    }
    if (v1) amp_resolve(xv1, amp1);

    float acc0[10], acc1[10];
#pragma unroll
    for (int c = 0; c < 10; ++c) { acc0[c] = 0.0f; acc1[c] = 0.0f; }

    // j-outer / c-inner: 10 independent accumulator chains, T wave-uniform
#pragma unroll
    for (int j = 0; j < 16; ++j) {
        float a0 = amp0[j], a1 = amp1[j];
#pragma unroll
        for (int c = 0; c < 10; ++c) {
            float tv = T[j * 10 + c];
            acc0[c] = fmaf(tv, a0, acc0[c]);
            acc1[c] = fmaf(tv, a1, acc1[c]);
        }
    }

    if (v0) {
#pragma unroll
        for (int c = 0; c < 10; ++c) sOut[tid * 10 + c] = acc0[c] * acc0[c];
    }
    if (v1) {
#pragma unroll
        for (int c = 0; c < 10; ++c) sOut[(256 + tid) * 10 + c] = acc1[c] * acc1[c];
    }
    __syncthreads();

    long long remain = (long long)nsamp - blockStart;
    if (remain >= SPB) {
        // full block: SPB*10 contiguous floats, 16B-aligned base
        float4* ov = (float4*)(out + blockStart * 10);
        const float4* sv = (const float4*)sOut;
#pragma unroll
        for (int i = tid; i < SPB * 10 / 4; i += 256)
            ov[i] = sv[i];
    } else if (remain > 0) {
        int n = (int)remain * 10;
        for (int i = tid; i < n; i += 256)
            out[blockStart * 10 + i] = sOut[i];
    }
}

extern "C" void kernel_launch(void* const* d_in, const int* in_sizes, int n_in,
                              void* d_out, int out_size, void* d_ws, size_t ws_size,
                              hipStream_t stream) {
    const float* x = (const float*)d_in[0];      // [B,4] f32
    const float* theta = (const float*)d_in[1];  // [8]   f32
    float* out = (float*)d_out;                  // [B,10] f32
    float* T = (float*)d_ws;                     // 160 floats scratch

    int nsamp = in_sizes[0] / 4;

    build_T<<<1, 192, 0, stream>>>(theta, T);

    int blocks = (nsamp + SPB - 1) / SPB;
    vqc_main<<<blocks, 256, 0, stream>>>((const float4*)x, T, out, nsamp);
}

// Round 4
// 37.574 us; speedup vs baseline: 1.0419x; 1.0273x over previous
//
#include <hip/hip_runtime.h>
#include <hip/hip_bf16.h>

// ---------------------------------------------------------------------------
// VQC_Net fully fused: probs[b, c] = ( sum_j U[c][j] * amp[b][j] )^2, c = 0..9
// U = RY2 * D * RY1 (16x16, theta-only). Each BLOCK rebuilds T = U (rows 0..9)
// into LDS (threads 0..159, one entry each) while the per-thread x-load is in
// flight; matvec reads T via wave-uniform ds_read_b128 (broadcast, no
// conflicts, no s_load stalls, no second kernel in the graph).
// amp build:
//   amp[0][k]  = prod_j ( (k>>j)&1 ? x0j : 1-x0j )                 (no sqrt)
//   amp[b][k]  = sqrt(hi)*sqrt(lo) factored, big-endian bits       (b >= 1)
// ---------------------------------------------------------------------------

#if defined(__has_builtin)
#if __has_builtin(__builtin_amdgcn_sqrtf)
#define FSQRT(x) __builtin_amdgcn_sqrtf(x)
#endif
#endif
#ifndef FSQRT
#define FSQRT(x) sqrtf(x)
#endif

__device__ __forceinline__ float ry_el(float c, float s, int i, int j) {
    return (i == j) ? c : (i ? s : -s);  // ry = [[c,-s],[s,c]]
}

// amp for the generic (b>=1) path: big-endian bits, squared probs, sqrt
__device__ __forceinline__ void amp_resolve(float4 xv, float amp[16]) {
    float p0 = xv.x * xv.x, p1 = xv.y * xv.y;
    float p2 = xv.z * xv.z, p3 = xv.w * xv.w;
    float hi[4] = { (1.0f - p0) * (1.0f - p1), (1.0f - p0) * p1,
                    p0 * (1.0f - p1),          p0 * p1 };
    float lo[4] = { (1.0f - p2) * (1.0f - p3), (1.0f - p2) * p3,
                    p2 * (1.0f - p3),          p2 * p3 };
    float sh[4], sl[4];
#pragma unroll
    for (int i = 0; i < 4; ++i) { sh[i] = FSQRT(hi[i]); sl[i] = FSQRT(lo[i]); }
#pragma unroll
    for (int k = 0; k < 16; ++k)
        amp[k] = sh[k >> 2] * sl[k & 3];
}

// amp for sample 0: little-endian bits, raw products, no sqrt
__device__ __forceinline__ void amp_prob2amp(float4 xv, float amp[16]) {
    float lo[4] = { (1.0f - xv.x) * (1.0f - xv.y), xv.x * (1.0f - xv.y),
                    (1.0f - xv.x) * xv.y,          xv.x * xv.y };
    float hi[4] = { (1.0f - xv.z) * (1.0f - xv.w), xv.z * (1.0f - xv.w),
                    (1.0f - xv.z) * xv.w,          xv.z * xv.w };
#pragma unroll
    for (int k = 0; k < 16; ++k)
        amp[k] = lo[k & 3] * hi[k >> 2];
}

__global__ __launch_bounds__(256) void vqc_fused(const float4* __restrict__ x,
                                                 const float* __restrict__ theta,
                                                 float* __restrict__ out,
                                                 int nsamp) {
    __shared__ float Tlds[160];   // T[c*16+j] = U[c][j], rows 0..9
    __shared__ float sOut[2560];  // 256 samples x 10 outputs, coalesced flush

    int tid = threadIdx.x;
    long long b = (long long)blockIdx.x * 256 + tid;
    bool valid = b < nsamp;

    // Issue the per-thread x load FIRST; T-build below hides its latency.
    float4 xv;
    if (valid) xv = x[b];

    // ---- per-block T build (threads 0..159, one U entry each) ----
    if (tid < 160) {
        int c = tid >> 4;   // row of U (class)
        int j = tid & 15;   // col of U (amp index)
        float co1[4], si1[4], co2[4], si2[4];
#pragma unroll
        for (int q = 0; q < 4; ++q) {
            float h1 = 0.5f * theta[q];
            float h2 = 0.5f * theta[4 + q];
            co1[q] = cosf(h1); si1[q] = sinf(h1);
            co2[q] = cosf(h2); si2[q] = sinf(h2);
        }
        float acc = 0.0f;
#pragma unroll
        for (int k = 0; k < 16; ++k) {
            int k0 = k & 1, k1 = (k >> 1) & 1, k2 = (k >> 2) & 1, k3 = (k >> 3) & 1;
            float r2 = ry_el(co2[0], si2[0], c & 1, k0)
                     * ry_el(co2[1], si2[1], (c >> 1) & 1, k1)
                     * ry_el(co2[2], si2[2], (c >> 2) & 1, k2)
                     * ry_el(co2[3], si2[3], (c >> 3) & 1, k3);
            float r1 = ry_el(co1[0], si1[0], k0, j & 1)
                     * ry_el(co1[1], si1[1], k1, (j >> 1) & 1)
                     * ry_el(co1[2], si1[2], k2, (j >> 2) & 1)
                     * ry_el(co1[3], si1[3], k3, (j >> 3) & 1);
            int sgn = (k0 & k1) ^ (k1 & k2) ^ (k2 & k3) ^ (k0 & k3);
            acc = fmaf(sgn ? -r2 : r2, r1, acc);
        }
        Tlds[tid] = acc;
    }
    __syncthreads();

    if (valid) {
        float amp[16];
        if (b == 0) amp_prob2amp(xv, amp);
        else        amp_resolve(xv, amp);

        // ---- 10x16 matvec, T via wave-uniform ds_read_b128 (broadcast) ----
        const float4* Tv = (const float4*)Tlds;
#pragma unroll
        for (int c = 0; c < 10; ++c) {
            float4 t0 = Tv[c * 4 + 0];
            float4 t1 = Tv[c * 4 + 1];
            float4 t2 = Tv[c * 4 + 2];
            float4 t3 = Tv[c * 4 + 3];
            // two partial chains for ILP
            float sa = 0.0f, sb = 0.0f;
            sa = fmaf(t0.x, amp[0],  sa); sb = fmaf(t0.y, amp[1],  sb);
            sa = fmaf(t0.z, amp[2],  sa); sb = fmaf(t0.w, amp[3],  sb);
            sa = fmaf(t1.x, amp[4],  sa); sb = fmaf(t1.y, amp[5],  sb);
            sa = fmaf(t1.z, amp[6],  sa); sb = fmaf(t1.w, amp[7],  sb);
            sa = fmaf(t2.x, amp[8],  sa); sb = fmaf(t2.y, amp[9],  sb);
            sa = fmaf(t2.z, amp[10], sa); sb = fmaf(t2.w, amp[11], sb);
            sa = fmaf(t3.x, amp[12], sa); sb = fmaf(t3.y, amp[13], sb);
            sa = fmaf(t3.z, amp[14], sa); sb = fmaf(t3.w, amp[15], sb);
            float s = sa + sb;
            sOut[tid * 10 + c] = s * s;
        }
    }
    __syncthreads();

    long long blockStart = (long long)blockIdx.x * 256;
    long long remain = (long long)nsamp - blockStart;
    if (remain >= 256) {
        // full block: 2560 contiguous floats, 16B-aligned base
        float4* ov = (float4*)(out + blockStart * 10);
        const float4* sv = (const float4*)sOut;
#pragma unroll
        for (int i = tid; i < 640; i += 256)
            ov[i] = sv[i];
    } else if (remain > 0) {
        int n = (int)remain * 10;
        for (int i = tid; i < n; i += 256)
            out[blockStart * 10 + i] = sOut[i];
    }
}

extern "C" void kernel_launch(void* const* d_in, const int* in_sizes, int n_in,
                              void* d_out, int out_size, void* d_ws, size_t ws_size,
                              hipStream_t stream) {
    const float* x = (const float*)d_in[0];      // [B,4] f32
    const float* theta = (const float*)d_in[1];  // [8]   f32
    float* out = (float*)d_out;                  // [B,10] f32

    int nsamp = in_sizes[0] / 4;
    int blocks = (nsamp + 255) / 256;
    vqc_fused<<<blocks, 256, 0, stream>>>((const float4*)x, theta, out, nsamp);
}

// Round 5
// 33.610 us; speedup vs baseline: 1.1648x; 1.1179x over previous
//
#include <hip/hip_runtime.h>
#include <hip/hip_bf16.h>

// ---------------------------------------------------------------------------
// VQC_Net: probs[b, c] = ( sum_j U[c][j] * amp[b][j] )^2,  c = 0..9
// R1-proven structure: T = U (rows 0..9) precomputed to d_ws by build_T;
// main kernel reads T with wave-uniform indices -> s_load (K$-hot after
// block 0 on each CU), c-outer matvec, LDS-staged coalesced output flush.
// R5 delta (scheduling only, math identical): persistent 4-tile grid-stride
// blocks + next-tile x prefetch + double-buffered sOut.
// amp build:
//   amp[0][k]  = prod_j ( (k>>j)&1 ? x0j : 1-x0j )                 (no sqrt)
//   amp[b][k]  = sqrt(hi)*sqrt(lo) factored, big-endian bits       (b >= 1)
// ---------------------------------------------------------------------------

__device__ __forceinline__ float ry_el(float c, float s, int i, int j) {
    return (i == j) ? c : (i ? s : -s);  // ry = [[c,-s],[s,c]]
}

__global__ void build_T(const float* __restrict__ theta, float* __restrict__ T) {
    int t = threadIdx.x;
    if (t >= 160) return;
    int c = t >> 4;   // row of U (class)
    int j = t & 15;   // col of U (amp index)

    float co1[4], si1[4], co2[4], si2[4];
#pragma unroll
    for (int q = 0; q < 4; ++q) {
        float h1 = 0.5f * theta[q];
        float h2 = 0.5f * theta[4 + q];
        co1[q] = cosf(h1); si1[q] = sinf(h1);
        co2[q] = cosf(h2); si2[q] = sinf(h2);
    }
    float acc = 0.0f;
#pragma unroll
    for (int k = 0; k < 16; ++k) {
        int k0 = k & 1, k1 = (k >> 1) & 1, k2 = (k >> 2) & 1, k3 = (k >> 3) & 1;
        float r2 = ry_el(co2[0], si2[0], c & 1, k0)
                 * ry_el(co2[1], si2[1], (c >> 1) & 1, k1)
                 * ry_el(co2[2], si2[2], (c >> 2) & 1, k2)
                 * ry_el(co2[3], si2[3], (c >> 3) & 1, k3);
        float r1 = ry_el(co1[0], si1[0], k0, j & 1)
                 * ry_el(co1[1], si1[1], k1, (j >> 1) & 1)
                 * ry_el(co1[2], si1[2], k2, (j >> 2) & 1)
                 * ry_el(co1[3], si1[3], k3, (j >> 3) & 1);
        int sgn = (k0 & k1) ^ (k1 & k2) ^ (k2 & k3) ^ (k0 & k3);
        acc = fmaf(sgn ? -r2 : r2, r1, acc);
    }
    T[c * 16 + j] = acc;   // row-major, matches matvec read order
}

// amp for the generic (b>=1) path: big-endian bits, squared probs, sqrt
__device__ __forceinline__ void amp_resolve(float4 xv, float amp[16]) {
    float p0 = xv.x * xv.x, p1 = xv.y * xv.y;
    float p2 = xv.z * xv.z, p3 = xv.w * xv.w;
    float hi[4] = { (1.0f - p0) * (1.0f - p1), (1.0f - p0) * p1,
                    p0 * (1.0f - p1),          p0 * p1 };
    float lo[4] = { (1.0f - p2) * (1.0f - p3), (1.0f - p2) * p3,
                    p2 * (1.0f - p3),          p2 * p3 };
    float sh[4], sl[4];
#pragma unroll
    for (int i = 0; i < 4; ++i) { sh[i] = sqrtf(hi[i]); sl[i] = sqrtf(lo[i]); }
#pragma unroll
    for (int k = 0; k < 16; ++k)
        amp[k] = sh[k >> 2] * sl[k & 3];
}

// amp for sample 0: little-endian bits, raw products, no sqrt
__device__ __forceinline__ void amp_prob2amp(float4 xv, float amp[16]) {
    float lo[4] = { (1.0f - xv.x) * (1.0f - xv.y), xv.x * (1.0f - xv.y),
                    (1.0f - xv.x) * xv.y,          xv.x * xv.y };
    float hi[4] = { (1.0f - xv.z) * (1.0f - xv.w), xv.z * (1.0f - xv.w),
                    (1.0f - xv.z) * xv.w,          xv.z * xv.w };
#pragma unroll
    for (int k = 0; k < 16; ++k)
        amp[k] = lo[k & 3] * hi[k >> 2];
}

#define TILES 4   // 4 x 256 samples per block; 2M / 1024 = 2048 blocks exact

__global__ __launch_bounds__(256) void vqc_main(const float4* __restrict__ x,
                                                const float* __restrict__ T,
                                                float* __restrict__ out,
                                                int nsamp) {
    __shared__ float sOut[2][2560];  // double-buffered: flush(t) || compute(t+1)

    int tid = threadIdx.x;
    long long base = (long long)blockIdx.x * (TILES * 256);

    // prefetch tile 0
    float4 xv;
    {
        long long b0 = base + tid;
        if (b0 < nsamp) xv = x[b0];
    }

    for (int t = 0; t < TILES; ++t) {
        long long tileStart = base + (long long)t * 256;
        long long remain = (long long)nsamp - tileStart;
        if (remain <= 0) break;           // uniform across block: safe

        long long b = tileStart + tid;
        bool valid = b < nsamp;
        int p = t & 1;
        float4 cur = xv;

        // issue next tile's load before the compute+barrier (latency overlap)
        if (t + 1 < TILES) {
            long long bn = b + 256;
            if (bn < nsamp) xv = x[bn];
        }

        if (valid) {
            float amp[16];
            if (b == 0) amp_prob2amp(cur, amp);
            else        amp_resolve(cur, amp);

            // 10x16 matvec; T[] indices wave-uniform -> scalar loads feed
            // v_fmac as the single SGPR operand. unroll 2: ~32 live T-SGPRs.
#pragma unroll 2
            for (int c = 0; c < 10; ++c) {
                float s = 0.0f;
#pragma unroll
                for (int jj = 0; jj < 16; ++jj)
                    s = fmaf(T[c * 16 + jj], amp[jj], s);
                sOut[p][tid * 10 + c] = s * s;
            }
        }
        __syncthreads();

        if (remain >= 256) {
            // full tile: 2560 contiguous floats, 16B-aligned base
            float4* ov = (float4*)(out + tileStart * 10);
            const float4* sv = (const float4*)sOut[p];
#pragma unroll
            for (int i = tid; i < 640; i += 256)
                ov[i] = sv[i];
        } else {
            int n = (int)remain * 10;
            for (int i = tid; i < n; i += 256)
                out[tileStart * 10 + i] = sOut[p][i];
        }
        // no second barrier needed: tile t+2's writes to buffer p happen only
        // after tile t+1's barrier, by which time every thread finished this
        // flush (program order before arriving at that barrier).
    }
}

extern "C" void kernel_launch(void* const* d_in, const int* in_sizes, int n_in,
                              void* d_out, int out_size, void* d_ws, size_t ws_size,
                              hipStream_t stream) {
    const float* x = (const float*)d_in[0];      // [B,4] f32
    const float* theta = (const float*)d_in[1];  // [8]   f32
    float* out = (float*)d_out;                  // [B,10] f32
    float* T = (float*)d_ws;                     // 160 floats scratch

    int nsamp = in_sizes[0] / 4;

    build_T<<<1, 192, 0, stream>>>(theta, T);

    int spb = TILES * 256;
    int blocks = (nsamp + spb - 1) / spb;
    vqc_main<<<blocks, 256, 0, stream>>>((const float4*)x, T, out, nsamp);
}

// Round 6
// 31.074 us; speedup vs baseline: 1.2598x; 1.0816x over previous
//
#include <hip/hip_runtime.h>
#include <hip/hip_bf16.h>

// ---------------------------------------------------------------------------
// VQC_Net: probs[b, c] = ( sum_j U[c][j] * amp[b][j] )^2,  c = 0..9
// Structure (R1-proven): T = U rows 0..9 precomputed to d_ws; main kernel
// reads T with wave-uniform indices (s_load, K$-hot), c-outer matvec,
// LDS-staged coalesced output flush; persistent 4-tile blocks (R5).
// R6 delta: raw s_barrier + manual lgkmcnt(0) instead of __syncthreads()
// -> per-tile barriers no longer drain vmcnt, so the 10 KB/tile global store
// burst streams under the next tile's compute (m97: __syncthreads emits
// s_waitcnt vmcnt(0) before s_barrier — that drain was the convoy).
// amp build:
//   amp[0][k]  = prod_j ( (k>>j)&1 ? x0j : 1-x0j )                 (no sqrt)
//   amp[b][k]  = sqrt(hi)*sqrt(lo) factored, big-endian bits       (b >= 1)
// ---------------------------------------------------------------------------

#if defined(__has_builtin)
#if __has_builtin(__builtin_amdgcn_sqrtf)
#define FSQRT(x) __builtin_amdgcn_sqrtf(x)
#endif
#endif
#ifndef FSQRT
#define FSQRT(x) sqrtf(x)
#endif

// Barrier that does NOT drain vmcnt: drain own LDS ops, then raw s_barrier.
// Each wave retires its own ds ops before arriving; after the barrier every
// wave's LDS traffic is therefore visible block-wide. Global stores are
// intentionally left in flight.
__device__ __forceinline__ void block_sync_lds_only() {
    asm volatile("s_waitcnt lgkmcnt(0)" ::: "memory");
    __builtin_amdgcn_s_barrier();
}

__device__ __forceinline__ float ry_el(float c, float s, int i, int j) {
    return (i == j) ? c : (i ? s : -s);  // ry = [[c,-s],[s,c]]
}

__global__ void build_T(const float* __restrict__ theta, float* __restrict__ T) {
    int t = threadIdx.x;
    if (t >= 160) return;
    int c = t >> 4;   // row of U (class)
    int j = t & 15;   // col of U (amp index)

    float co1[4], si1[4], co2[4], si2[4];
#pragma unroll
    for (int q = 0; q < 4; ++q) {
        float h1 = 0.5f * theta[q];
        float h2 = 0.5f * theta[4 + q];
        co1[q] = cosf(h1); si1[q] = sinf(h1);
        co2[q] = cosf(h2); si2[q] = sinf(h2);
    }
    float acc = 0.0f;
#pragma unroll
    for (int k = 0; k < 16; ++k) {
        int k0 = k & 1, k1 = (k >> 1) & 1, k2 = (k >> 2) & 1, k3 = (k >> 3) & 1;
        float r2 = ry_el(co2[0], si2[0], c & 1, k0)
                 * ry_el(co2[1], si2[1], (c >> 1) & 1, k1)
                 * ry_el(co2[2], si2[2], (c >> 2) & 1, k2)
                 * ry_el(co2[3], si2[3], (c >> 3) & 1, k3);
        float r1 = ry_el(co1[0], si1[0], k0, j & 1)
                 * ry_el(co1[1], si1[1], k1, (j >> 1) & 1)
                 * ry_el(co1[2], si1[2], k2, (j >> 2) & 1)
                 * ry_el(co1[3], si1[3], k3, (j >> 3) & 1);
        int sgn = (k0 & k1) ^ (k1 & k2) ^ (k2 & k3) ^ (k0 & k3);
        acc = fmaf(sgn ? -r2 : r2, r1, acc);
    }
    T[c * 16 + j] = acc;   // row-major, matches matvec read order
}

// amp for the generic (b>=1) path: big-endian bits, squared probs, sqrt
__device__ __forceinline__ void amp_resolve(float4 xv, float amp[16]) {
    float p0 = xv.x * xv.x, p1 = xv.y * xv.y;
    float p2 = xv.z * xv.z, p3 = xv.w * xv.w;
    float hi[4] = { (1.0f - p0) * (1.0f - p1), (1.0f - p0) * p1,
                    p0 * (1.0f - p1),          p0 * p1 };
    float lo[4] = { (1.0f - p2) * (1.0f - p3), (1.0f - p2) * p3,
                    p2 * (1.0f - p3),          p2 * p3 };
    float sh[4], sl[4];
#pragma unroll
    for (int i = 0; i < 4; ++i) { sh[i] = FSQRT(hi[i]); sl[i] = FSQRT(lo[i]); }
#pragma unroll
    for (int k = 0; k < 16; ++k)
        amp[k] = sh[k >> 2] * sl[k & 3];
}

// amp for sample 0: little-endian bits, raw products, no sqrt
__device__ __forceinline__ void amp_prob2amp(float4 xv, float amp[16]) {
    float lo[4] = { (1.0f - xv.x) * (1.0f - xv.y), xv.x * (1.0f - xv.y),
                    (1.0f - xv.x) * xv.y,          xv.x * xv.y };
    float hi[4] = { (1.0f - xv.z) * (1.0f - xv.w), xv.z * (1.0f - xv.w),
                    (1.0f - xv.z) * xv.w,          xv.z * xv.w };
#pragma unroll
    for (int k = 0; k < 16; ++k)
        amp[k] = lo[k & 3] * hi[k >> 2];
}

#define TILES 4   // 4 x 256 samples per block; 2M / 1024 = 2048 blocks exact

__global__ __launch_bounds__(256, 8) void vqc_main(const float4* __restrict__ x,
                                                   const float* __restrict__ T,
                                                   float* __restrict__ out,
                                                   int nsamp) {
    __shared__ float sOut[2][2560];  // double-buffered: flush(t) || compute(t+1)

    int tid = threadIdx.x;
    long long base = (long long)blockIdx.x * (TILES * 256);

    // prefetch tile 0
    float4 xv;
    {
        long long b0 = base + tid;
        if (b0 < nsamp) xv = x[b0];
    }

    for (int t = 0; t < TILES; ++t) {
        long long tileStart = base + (long long)t * 256;
        long long remain = (long long)nsamp - tileStart;
        if (remain <= 0) break;           // uniform across block: safe

        long long b = tileStart + tid;
        bool valid = b < nsamp;
        int p = t & 1;
        float4 cur = xv;

        // issue next tile's load before the compute+barrier (latency overlap)
        if (t + 1 < TILES) {
            long long bn = b + 256;
            if (bn < nsamp) xv = x[bn];
        }

        if (valid) {
            float amp[16];
            if (b == 0) amp_prob2amp(cur, amp);
            else        amp_resolve(cur, amp);

            // 10x16 matvec; T[] indices wave-uniform -> scalar loads feed
            // v_fmac as the single SGPR operand. unroll 2: ~32 live T-SGPRs.
#pragma unroll 2
            for (int c = 0; c < 10; ++c) {
                float s = 0.0f;
#pragma unroll
                for (int jj = 0; jj < 16; ++jj)
                    s = fmaf(T[c * 16 + jj], amp[jj], s);
                sOut[p][tid * 10 + c] = s * s;
            }
        }
        block_sync_lds_only();   // LDS-visible barrier; global stores stay in flight

        if (remain >= 256) {
            // full tile: 2560 contiguous floats, 16B-aligned base
            float4* ov = (float4*)(out + tileStart * 10);
            const float4* sv = (const float4*)sOut[p];
#pragma unroll
            for (int i = tid; i < 640; i += 256)
                ov[i] = sv[i];
        } else {
            int n = (int)remain * 10;
            for (int i = tid; i < n; i += 256)
                out[tileStart * 10 + i] = sOut[p][i];
        }
        // WAR on buffer p (reused at t+2) is protected by tile t+1's barrier:
        // each wave drains its flush ds_reads (lgkmcnt) before arriving there.
    }
}

extern "C" void kernel_launch(void* const* d_in, const int* in_sizes, int n_in,
                              void* d_out, int out_size, void* d_ws, size_t ws_size,
                              hipStream_t stream) {
    const float* x = (const float*)d_in[0];      // [B,4] f32
    const float* theta = (const float*)d_in[1];  // [8]   f32
    float* out = (float*)d_out;                  // [B,10] f32
    float* T = (float*)d_ws;                     // 160 floats scratch

    int nsamp = in_sizes[0] / 4;

    build_T<<<1, 192, 0, stream>>>(theta, T);

    int spb = TILES * 256;
    int blocks = (nsamp + spb - 1) / spb;
    vqc_main<<<blocks, 256, 0, stream>>>((const float4*)x, T, out, nsamp);
}